// Round 14
// baseline (607.028 us; speedup 1.0000x reference)
//
#include <hip/hip_runtime.h>
#include <hip/hip_bf16.h>

#define BDIM 256
constexpr int Bc = 4, Hc = 128, Wcn = 128, Cc = 768, WM = 65, NB = 8, BS = 96;
constexpr int NROWS = Bc * WM * Hc;              // 33280 spectral rows (b, wm, h)
constexpr size_t NSPEC = (size_t)NROWS * Cc;     // 25,559,040 elems per r/i plane

typedef __attribute__((ext_vector_type(8))) _Float16 f16x8;
typedef __attribute__((ext_vector_type(4))) float f32x4;
typedef __attribute__((ext_vector_type(4))) unsigned int u32x4;

__device__ __forceinline__ unsigned short f2h(float f) {
    return __builtin_bit_cast(unsigned short, (_Float16)f);
}
__device__ __forceinline__ float h2f(unsigned short s) {
    return (float)__builtin_bit_cast(_Float16, s);
}
// vmcnt-preserving barrier, FENCED both sides (R9 lesson: raw s_barrier is
// not a compiler fence; LDS ops must not be scheduled across it).
__device__ __forceinline__ void barx() {
    __builtin_amdgcn_sched_barrier(0);
    asm volatile("s_waitcnt lgkmcnt(0)" ::: "memory");
    __builtin_amdgcn_s_barrier();
    __builtin_amdgcn_sched_barrier(0);
    asm volatile("" ::: "memory");
}

// ---------------- Kprep: transpose MLP weights to f16 [mat][blk][n][k] ------
__global__ __launch_bounds__(BDIM) void kprep(const float* __restrict__ w1,
                                              const float* __restrict__ w2,
                                              unsigned short* __restrict__ WTg) {
    int idx = blockIdx.x * BDIM + threadIdx.x;   // 4*8*96*96 = 294,912
    if (idx >= 294912) return;
    int k = idx % 96, n = (idx / 96) % 96, blk = (idx / 9216) % 8, mat = idx / 73728;
    const float* src = (mat < 2) ? w1 : w2;
    int q = mat & 1;
    WTg[idx] = f2h(src[(((size_t)q * 8 + blk) * 96 + k) * 96 + n]);
}

// ---------------- K1m: rfft over W via f16 MFMA (scale 1/128) ---------------
constexpr int K1PAD = 136;
__global__ __launch_bounds__(BDIM, 1) void k1m(const float* __restrict__ x,
                                               unsigned short* __restrict__ Rr,
                                               unsigned short* __restrict__ Ri) {
    __shared__ unsigned short Xt[64][K1PAD];
    const int tid = threadIdx.x;
    const int lane = tid & 63;
    const int wv = tid >> 6;
    const int b = blockIdx.x >> 7, h = blockIdx.x & 127;
    const float* xp = x + ((size_t)(b * 16384 + h * 128)) * 768;
    const size_t sbase = ((size_t)(b * WM) * 128 + h) * 768;

    f16x8 Af[2][4];
    {
        const int rlo = wv * 32 + (lane & 15);
        #pragma unroll
        for (int rf = 0; rf < 2; ++rf) {
            const int r = rlo + rf * 16;
            const int m = (r < 65) ? r : (r - 64);
            #pragma unroll
            for (int ks = 0; ks < 4; ++ks) {
                f16x8 v;
                #pragma unroll
                for (int j = 0; j < 8; ++j) {
                    int k = ks * 32 + ((lane >> 4) << 3) + j;
                    float th = (float)((m * k) & 127) * 0.04908738521234052f;
                    float s, c; __sincosf(th, &s, &c);
                    v[j] = (_Float16)(((r < 65) ? c : -s) * 0.0078125f);
                }
                Af[rf][ks] = v;
            }
        }
    }

    const int w = tid & 127, cg = tid >> 7;
    float4 pfv[8];
    #pragma unroll
    for (int q = 0; q < 8; ++q)
        pfv[q] = *(const float4*)(xp + (size_t)w * 768 + cg * 32 + q * 4);

    const int koff = (lane >> 4) << 3;

    for (int t = 0; t < 12; ++t) {
        #pragma unroll
        for (int q = 0; q < 8; ++q) {
            float4 v = pfv[q];
            int cb = cg * 32 + q * 4;
            Xt[cb + 0][w] = f2h(v.x);
            Xt[cb + 1][w] = f2h(v.y);
            Xt[cb + 2][w] = f2h(v.z);
            Xt[cb + 3][w] = f2h(v.w);
        }
        if (t < 11) {
            #pragma unroll
            for (int q = 0; q < 8; ++q)
                pfv[q] = *(const float4*)(xp + (size_t)w * 768 + (t + 1) * 64 + cg * 32 + q * 4);
        }
        barx();

        f32x4 acc[2][4];
        #pragma unroll
        for (int rf = 0; rf < 2; ++rf)
            #pragma unroll
            for (int cf = 0; cf < 4; ++cf)
                acc[rf][cf] = (f32x4){0, 0, 0, 0};
        #pragma unroll
        for (int ks = 0; ks < 4; ++ks) {
            #pragma unroll
            for (int cf = 0; cf < 4; ++cf) {
                const int cl = cf * 16 + (lane & 15);
                f16x8 Bf = *(const f16x8*)(&Xt[cl][ks * 32 + koff]);
                #pragma unroll
                for (int rf = 0; rf < 2; ++rf)
                    acc[rf][cf] = __builtin_amdgcn_mfma_f32_16x16x32_f16(Af[rf][ks], Bf, acc[rf][cf], 0, 0, 0);
            }
        }
        #pragma unroll
        for (int rf = 0; rf < 2; ++rf)
            #pragma unroll
            for (int cf = 0; cf < 4; ++cf) {
                int col = t * 64 + cf * 16 + (lane & 15);
                int r0 = wv * 32 + rf * 16 + ((lane >> 4) << 2);
                #pragma unroll
                for (int reg = 0; reg < 4; ++reg) {
                    int r = r0 + reg;
                    if (r < 65) {
                        Rr[sbase + (size_t)r * 98304 + col] = f2h(acc[rf][cf][reg]);
                        if (r == 0)  Ri[sbase + col] = 0;
                        if (r == 64) Ri[sbase + (size_t)64 * 98304 + col] = 0;
                    } else {
                        Ri[sbase + (size_t)(r - 64) * 98304 + col] = f2h(acc[rf][cf][reg]);
                    }
                }
            }
        barx();
    }
}

// ---------------- Kmid v5: PERSISTENT fused fwd-DFT -> MLP -> inv-DFT -------
// grid (32, 8) = 256 wgs (1/CU); each wg owns slabs tau = wgx+32k (8-9).
// Loop-invariant: weights in LDS WT[384][104] (once), twiddles in 64 regs
// (once; phase C reuses with sign-flip at use). Next slab's X prefetched in
// phase C, kept in flight across fenced barriers (vmcnt never drained).
// LDS 132,096 B: WT | Xt{r,i}[96][136] (Xt unioned as Y[128][200]).
constexpr int KMT = 136;
constexpr int WTP = 104;
__global__ __launch_bounds__(BDIM) void kmid(unsigned short* __restrict__ Rr,
                                             unsigned short* __restrict__ Ri,
                                             const unsigned short* __restrict__ WTg,
                                             const float* __restrict__ b1,
                                             const float* __restrict__ b2) {
    extern __shared__ unsigned short lds[];
    unsigned short* WT  = lds;                   // [384][104] rows: mat*96+n
    unsigned short* Xtr = WT + 384 * WTP;        // [96][136]
    unsigned short* Xti = Xtr + 96 * KMT;        // [96][136]
    unsigned short* Y   = Xtr;                   // [128][200] (union)

    const int tid = threadIdx.x;
    const int lane = tid & 63;
    const int wv = tid >> 6;
    const int blk = blockIdx.y;
    const int wgx = blockIdx.x;

    const int hme = tid & 127, cgme = tid >> 7;
    const int arow0 = wv * 32 + (lane & 15);
    const int koff = (lane >> 4) << 3;
    const int rowoff = (lane >> 4) << 2;
    const int n0 = wv * 48;

    // ---- issue slab-0 X loads first (hide under prologue)
    u32x4 pfs[12];
    {
        size_t sb = (size_t)wgx * 98304;
        #pragma unroll
        for (int p = 0; p < 12; ++p) {
            const unsigned short* src = (p >= 6) ? Ri : Rr;
            int cg = (p % 6) * 2 + cgme;
            pfs[p] = *(const u32x4*)(src + sb + (size_t)hme * 768 + blk * 96 + cg * 8);
        }
    }

    // ---- stage weights into LDS (once): 4608 vec8 moves, 18/thread
    #pragma unroll
    for (int i = 0; i < 18; ++i) {
        int v = tid + i * BDIM;            // < 4608
        int r = v / 12, kg = v % 12;
        const unsigned short* src = WTg + (size_t)(r / 96) * 73728 + (size_t)blk * 9216
                                        + (r % 96) * 96 + kg * 8;
        *(u32x4*)(WT + r * WTP + kg * 8) = *(const u32x4*)src;
    }

    // ---- biases
    float bias1[3], bias2[3];
    int nq_c[3], nl_c[3];
    #pragma unroll
    for (int c = 0; c < 3; ++c) {
        int n = n0 + c * 16 + (lane & 15);
        bias1[c] = (n < 96) ? b1[blk * 96 + n] : b1[768 + blk * 96 + (n - 96)];
        bias2[c] = (n < 96) ? b2[blk * 96 + n] : b2[768 + blk * 96 + (n - 96)];
        nq_c[c] = (n0 + c * 16) < 96;
        nl_c[c] = n0 + c * 16 + (lane & 15) - (nq_c[c] ? 0 : 96);
    }

    // ---- twiddles once into registers (phase A form: Ca=cos, Sa=+sin)
    f16x8 Ca[2][4], Sa[2][4];
    #pragma unroll
    for (int rf = 0; rf < 2; ++rf) {
        const int r = arow0 + rf * 16;
        #pragma unroll
        for (int ks = 0; ks < 4; ++ks) {
            f16x8 cv, sv;
            #pragma unroll
            for (int j = 0; j < 8; ++j) {
                int k = ks * 32 + koff + j;
                float th = (float)((r * k) & 127) * 0.04908738521234052f;
                float s, c; __sincosf(th, &s, &c);
                cv[j] = (_Float16)c;
                sv[j] = (_Float16)s;
            }
            Ca[rf][ks] = cv;
            Sa[rf][ks] = sv;
        }
    }
    __syncthreads();   // prologue done: WT staged (slab-0 loads drained, fine)

    for (int tau = wgx; tau < 260; tau += 32) {
        const size_t sbase = (size_t)tau * 98304;

        // ---- scatter prefetched X into Xt[c][h] (h lane-major)
        #pragma unroll
        for (int p = 0; p < 12; ++p) {
            unsigned short* dst = (p >= 6) ? Xti : Xtr;
            int cl = ((p % 6) * 2 + cgme) * 8;
            unsigned short tmp[8];
            *(u32x4*)&tmp[0] = pfs[p];
            #pragma unroll
            for (int j = 0; j < 8; ++j)
                dst[(cl + j) * KMT + hme] = tmp[j];
        }
        barx();   // #1: X staged

        // ---- phase A: fwd H-DFT (Yr = C.Xr + S.Xi ; Yi = C.Xi - S.Xr)
        f32x4 accr[2][6], acci[2][6];
        #pragma unroll
        for (int rf = 0; rf < 2; ++rf)
            #pragma unroll
            for (int cf = 0; cf < 6; ++cf) {
                accr[rf][cf] = (f32x4){0, 0, 0, 0};
                acci[rf][cf] = (f32x4){0, 0, 0, 0};
            }
        #pragma unroll
        for (int ks = 0; ks < 4; ++ks) {
            f16x8 Sn[2];
            #pragma unroll
            for (int rf = 0; rf < 2; ++rf) {
                u32x4 u = __builtin_bit_cast(u32x4, Sa[rf][ks]);
                u ^= 0x80008000u;
                Sn[rf] = __builtin_bit_cast(f16x8, u);
            }
            #pragma unroll
            for (int cf = 0; cf < 6; ++cf) {
                int boff = (cf * 16 + (lane & 15)) * KMT + ks * 32 + koff;
                f16x8 Br = *(const f16x8*)(Xtr + boff);
                f16x8 Bi = *(const f16x8*)(Xti + boff);
                #pragma unroll
                for (int rf = 0; rf < 2; ++rf) {
                    accr[rf][cf] = __builtin_amdgcn_mfma_f32_16x16x32_f16(Ca[rf][ks], Br, accr[rf][cf], 0, 0, 0);
                    accr[rf][cf] = __builtin_amdgcn_mfma_f32_16x16x32_f16(Sa[rf][ks], Bi, accr[rf][cf], 0, 0, 0);
                    acci[rf][cf] = __builtin_amdgcn_mfma_f32_16x16x32_f16(Ca[rf][ks], Bi, acci[rf][cf], 0, 0, 0);
                    acci[rf][cf] = __builtin_amdgcn_mfma_f32_16x16x32_f16(Sn[rf], Br, acci[rf][cf], 0, 0, 0);
                }
            }
        }
        barx();   // #2: Xt reads done; region becomes Y

        // ---- write Y [pos][k] augmented
        #pragma unroll
        for (int rf = 0; rf < 2; ++rf)
            #pragma unroll
            for (int cf = 0; cf < 6; ++cf) {
                int c = cf * 16 + (lane & 15);
                #pragma unroll
                for (int reg = 0; reg < 4; ++reg) {
                    int row = wv * 32 + rf * 16 + rowoff + reg;
                    Y[row * 200 + c]      = f2h(accr[rf][cf][reg]);
                    Y[row * 200 + 96 + c] = f2h(acci[rf][cf][reg]);
                }
            }
        barx();   // #3: Y visible

        // ---- phase B: MLP layer 1 (weights from LDS WT)
        const unsigned short* Xl = Y + (lane & 15) * 200 + koff;
        f32x4 acc[8][3];
        #pragma unroll
        for (int r = 0; r < 8; ++r)
            #pragma unroll
            for (int c = 0; c < 3; ++c)
                acc[r][c] = (f32x4){bias1[c], bias1[c], bias1[c], bias1[c]};
        #pragma unroll
        for (int kit = 0; kit < 6; ++kit) {
            const int kq = kit < 3;
            const int kl = kit * 32 + koff - (kq ? 0 : 96);
            f16x8 Bf[3];
            #pragma unroll
            for (int c = 0; c < 3; ++c) {
                const int quad = kq ? (nq_c[c] ? 0 : 1) : (nq_c[c] ? 1 : 0);
                f16x8 v = *(const f16x8*)(WT + (quad * 96 + nl_c[c]) * WTP + kl);
                if ((!kq) && nq_c[c]) { u32x4 u = __builtin_bit_cast(u32x4, v); u ^= 0x80008000u; v = __builtin_bit_cast(f16x8, u); }
                Bf[c] = v;
            }
            f16x8 A[8];
            #pragma unroll
            for (int r = 0; r < 8; ++r)
                A[r] = *(const f16x8*)(Xl + r * 3200 + kit * 32);
            #pragma unroll
            for (int r = 0; r < 8; ++r)
                #pragma unroll
                for (int c = 0; c < 3; ++c)
                    acc[r][c] = __builtin_amdgcn_mfma_f32_16x16x32_f16(A[r], Bf[c], acc[r][c], 0, 0, 0);
        }
        barx();   // #4: layer-1 A-reads done
        #pragma unroll
        for (int r = 0; r < 8; ++r)
            #pragma unroll
            for (int c = 0; c < 3; ++c) {
                int ncol = n0 + c * 16 + (lane & 15);
                #pragma unroll
                for (int reg = 0; reg < 4; ++reg) {
                    int row = r * 16 + rowoff + reg;
                    Y[row * 200 + ncol] = f2h(fmaxf(acc[r][c][reg], 0.f));
                }
            }
        barx();   // #5: O1 visible

        // ---- layer 2 + softshrink
        #pragma unroll
        for (int r = 0; r < 8; ++r)
            #pragma unroll
            for (int c = 0; c < 3; ++c)
                acc[r][c] = (f32x4){bias2[c], bias2[c], bias2[c], bias2[c]};
        #pragma unroll
        for (int kit = 0; kit < 6; ++kit) {
            const int kq = kit < 3;
            const int kl = kit * 32 + koff - (kq ? 0 : 96);
            f16x8 Bf[3];
            #pragma unroll
            for (int c = 0; c < 3; ++c) {
                const int quad = kq ? (nq_c[c] ? 0 : 1) : (nq_c[c] ? 1 : 0);
                f16x8 v = *(const f16x8*)(WT + ((2 + quad) * 96 + nl_c[c]) * WTP + kl);
                if ((!kq) && nq_c[c]) { u32x4 u = __builtin_bit_cast(u32x4, v); u ^= 0x80008000u; v = __builtin_bit_cast(f16x8, u); }
                Bf[c] = v;
            }
            f16x8 A[8];
            #pragma unroll
            for (int r = 0; r < 8; ++r)
                A[r] = *(const f16x8*)(Xl + r * 3200 + kit * 32);
            #pragma unroll
            for (int r = 0; r < 8; ++r)
                #pragma unroll
                for (int c = 0; c < 3; ++c)
                    acc[r][c] = __builtin_amdgcn_mfma_f32_16x16x32_f16(A[r], Bf[c], acc[r][c], 0, 0, 0);
        }
        barx();   // #6: layer-2 A-reads done; region becomes Xt again
        // ---- write O2 transposed into Xt[c][h2] with softshrink
        #pragma unroll
        for (int r = 0; r < 8; ++r)
            #pragma unroll
            for (int c = 0; c < 3; ++c) {
                int ncol = n0 + c * 16 + (lane & 15);
                unsigned short* dst = (ncol < 96) ? Xtr : Xti;
                int cc = (ncol < 96) ? ncol : ncol - 96;
                #pragma unroll
                for (int reg = 0; reg < 4; ++reg) {
                    int row = r * 16 + rowoff + reg;
                    float v = acc[r][c][reg];
                    v = (v > 0.01f) ? v - 0.01f : ((v < -0.01f) ? v + 0.01f : 0.f);
                    dst[cc * KMT + row] = f2h(v);
                }
            }
        barx();   // #7: O2t visible

        // ---- issue NEXT slab's X loads (in flight through phase C + store)
        if (tau + 32 < 260) {
            size_t sb = (size_t)(tau + 32) * 98304;
            #pragma unroll
            for (int p = 0; p < 12; ++p) {
                const unsigned short* src = (p >= 6) ? Ri : Rr;
                int cg = (p % 6) * 2 + cgme;
                pfs[p] = *(const u32x4*)(src + sb + (size_t)hme * 768 + blk * 96 + cg * 8);
            }
        }

        // ---- phase C: inverse H-DFT (Zr = C.Or - S.Oi ; Zi = C.Oi + S.Or)
        #pragma unroll
        for (int rf = 0; rf < 2; ++rf)
            #pragma unroll
            for (int cf = 0; cf < 6; ++cf) {
                accr[rf][cf] = (f32x4){0, 0, 0, 0};
                acci[rf][cf] = (f32x4){0, 0, 0, 0};
            }
        #pragma unroll
        for (int ks = 0; ks < 4; ++ks) {
            f16x8 Sn[2];
            #pragma unroll
            for (int rf = 0; rf < 2; ++rf) {
                u32x4 u = __builtin_bit_cast(u32x4, Sa[rf][ks]);
                u ^= 0x80008000u;
                Sn[rf] = __builtin_bit_cast(f16x8, u);
            }
            #pragma unroll
            for (int cf = 0; cf < 6; ++cf) {
                int boff = (cf * 16 + (lane & 15)) * KMT + ks * 32 + koff;
                f16x8 Br = *(const f16x8*)(Xtr + boff);
                f16x8 Bi = *(const f16x8*)(Xti + boff);
                #pragma unroll
                for (int rf = 0; rf < 2; ++rf) {
                    accr[rf][cf] = __builtin_amdgcn_mfma_f32_16x16x32_f16(Ca[rf][ks], Br, accr[rf][cf], 0, 0, 0);
                    accr[rf][cf] = __builtin_amdgcn_mfma_f32_16x16x32_f16(Sn[rf], Bi, accr[rf][cf], 0, 0, 0);
                    acci[rf][cf] = __builtin_amdgcn_mfma_f32_16x16x32_f16(Ca[rf][ks], Bi, acci[rf][cf], 0, 0, 0);
                    acci[rf][cf] = __builtin_amdgcn_mfma_f32_16x16x32_f16(Sa[rf][ks], Br, acci[rf][cf], 0, 0, 0);
                }
            }
        }
        // ---- store to global spectral planes (in place)
        #pragma unroll
        for (int rf = 0; rf < 2; ++rf)
            #pragma unroll
            for (int cf = 0; cf < 6; ++cf) {
                int c = blk * 96 + cf * 16 + (lane & 15);
                int h0 = wv * 32 + rf * 16 + rowoff;
                #pragma unroll
                for (int reg = 0; reg < 4; ++reg) {
                    size_t a = sbase + (size_t)(h0 + reg) * 768 + c;
                    Rr[a] = f2h(accr[rf][cf][reg]);
                    Ri[a] = f2h(acci[rf][cf][reg]);
                }
            }
        barx();   // #8: Xt reads (phase C) done before next scatter
    }
}

// ---------------- K5m: c2r inverse over W via f16 MFMA + residual -----------
constexpr int K5PAD = 104;
__global__ __launch_bounds__(BDIM, 1) void k5m(const unsigned short* __restrict__ Rr,
                                               const unsigned short* __restrict__ Ri,
                                               const float* __restrict__ x,
                                               float* __restrict__ out) {
    __shared__ unsigned short Xt[2][64][K5PAD];
    const int tid = threadIdx.x;
    const int lane = tid & 63;
    const int wv = tid >> 6;
    const int b = blockIdx.x >> 7, h = blockIdx.x & 127;
    const size_t rowbase = ((size_t)(b * WM) * 128 + h) * 768;
    const size_t obase = ((size_t)(b * 16384 + h * 128)) * 768;

    f16x8 Ca[2][3], Sa[2][3];
    {
        const int wrow_lo = wv * 32 + (lane & 15);
        #pragma unroll
        for (int rf = 0; rf < 2; ++rf) {
            const int wrow = wrow_lo + rf * 16;
            #pragma unroll
            for (int ks = 0; ks < 3; ++ks) {
                f16x8 cv, sv;
                #pragma unroll
                for (int j = 0; j < 8; ++j) {
                    int wm = ks * 32 + ((lane >> 4) << 3) + j;
                    float alpha = (wm > 64) ? 0.f : ((wm == 0 || wm == 64) ? 1.f : 2.f);
                    float th = (float)((wrow * wm) & 127) * 0.04908738521234052f;
                    float s, c; __sincosf(th, &s, &c);
                    cv[j] = (_Float16)(alpha * 0.0078125f * c);
                    sv[j] = (_Float16)(-alpha * 0.0078125f * s);
                }
                Ca[rf][ks] = cv;
                Sa[rf][ks] = sv;
            }
        }
    }

    for (int idx = tid; idx < 2 * 64 * 31; idx += BDIM) {
        int plane = idx / (64 * 31), rem = idx % (64 * 31);
        int cl = rem / 31, wm = 65 + rem % 31;
        Xt[plane][cl][wm] = 0;
    }

    unsigned short pfs[4][8], pfn[8];
    #pragma unroll
    for (int i = 0; i < 4; ++i) {
        const unsigned short* src = (i >> 1) ? Ri : Rr;
        int grp = (i & 1) * 4 + wv;
        *(u32x4*)&pfs[i][0] = *(const u32x4*)(src + rowbase + (size_t)lane * 98304 + grp * 8);
    }
    if (tid < 16) {
        const unsigned short* src = (tid >> 3) ? Ri : Rr;
        *(u32x4*)&pfn[0] = *(const u32x4*)(src + rowbase + (size_t)64 * 98304 + (tid & 7) * 8);
    }

    for (int t = 0; t < 12; ++t) {
        #pragma unroll
        for (int i = 0; i < 4; ++i) {
            int plane = i >> 1, grp = (i & 1) * 4 + wv;
            #pragma unroll
            for (int j = 0; j < 8; ++j)
                Xt[plane][grp * 8 + j][lane] = pfs[i][j];
        }
        if (tid < 16) {
            int plane = tid >> 3, grp = tid & 7;
            #pragma unroll
            for (int j = 0; j < 8; ++j)
                Xt[plane][grp * 8 + j][64] = pfn[j];
        }
        if (t < 11) {
            #pragma unroll
            for (int i = 0; i < 4; ++i) {
                const unsigned short* src = (i >> 1) ? Ri : Rr;
                int grp = (i & 1) * 4 + wv;
                *(u32x4*)&pfs[i][0] = *(const u32x4*)(src + rowbase + (size_t)lane * 98304 + (t + 1) * 64 + grp * 8);
            }
            if (tid < 16) {
                const unsigned short* src = (tid >> 3) ? Ri : Rr;
                *(u32x4*)&pfn[0] = *(const u32x4*)(src + rowbase + (size_t)64 * 98304 + (t + 1) * 64 + (tid & 7) * 8);
            }
        }
        barx();

        f32x4 acc[2][4];
        #pragma unroll
        for (int rf = 0; rf < 2; ++rf)
            #pragma unroll
            for (int cf = 0; cf < 4; ++cf)
                acc[rf][cf] = (f32x4){0, 0, 0, 0};
        const int koff = (lane >> 4) << 3;
        #pragma unroll
        for (int ks = 0; ks < 3; ++ks) {
            #pragma unroll
            for (int cf = 0; cf < 4; ++cf) {
                const int cl = cf * 16 + (lane & 15);
                f16x8 Br = *(const f16x8*)(&Xt[0][cl][ks * 32 + koff]);
                f16x8 Bi = *(const f16x8*)(&Xt[1][cl][ks * 32 + koff]);
                #pragma unroll
                for (int rf = 0; rf < 2; ++rf) {
                    acc[rf][cf] = __builtin_amdgcn_mfma_f32_16x16x32_f16(Ca[rf][ks], Br, acc[rf][cf], 0, 0, 0);
                    acc[rf][cf] = __builtin_amdgcn_mfma_f32_16x16x32_f16(Sa[rf][ks], Bi, acc[rf][cf], 0, 0, 0);
                }
            }
        }
        #pragma unroll
        for (int rf = 0; rf < 2; ++rf)
            #pragma unroll
            for (int cf = 0; cf < 4; ++cf) {
                int col = t * 64 + cf * 16 + (lane & 15);
                int row0 = wv * 32 + rf * 16 + ((lane >> 4) << 2);
                #pragma unroll
                for (int reg = 0; reg < 4; ++reg) {
                    size_t a = obase + (size_t)(row0 + reg) * 768 + col;
                    out[a] = acc[rf][cf][reg] + x[a];
                }
            }
        barx();
    }
}

extern "C" void kernel_launch(void* const* d_in, const int* in_sizes, int n_in,
                              void* d_out, int out_size, void* d_ws, size_t ws_size,
                              hipStream_t stream) {
    const float* x  = (const float*)d_in[0];
    const float* w1 = (const float*)d_in[1];
    const float* b1 = (const float*)d_in[2];
    const float* w2 = (const float*)d_in[3];
    const float* b2 = (const float*)d_in[4];
    float* out = (float*)d_out;

    unsigned short* Rr = (unsigned short*)d_ws;
    unsigned short* Ri = Rr + NSPEC;
    unsigned short* WTg = Ri + NSPEC;            // 294,912 f16 = 0.6 MB

    const size_t kmlds = (size_t)(384 * WTP + 2 * 96 * KMT) * 2;  // 132,096 B

    kprep<<<dim3(1152), BDIM, 0, stream>>>(w1, w2, WTg);
    k1m<<<dim3(512), BDIM, 0, stream>>>(x, Rr, Ri);
    kmid<<<dim3(32, 8), BDIM, kmlds, stream>>>(Rr, Ri, WTg, b1, b2);
    k5m<<<dim3(512), BDIM, 0, stream>>>(Rr, Ri, x, out);
}

// Round 15
// 358.432 us; speedup vs baseline: 1.6936x; 1.6936x over previous
//
#include <hip/hip_runtime.h>
#include <hip/hip_bf16.h>

#define BDIM 256
constexpr int Bc = 4, Hc = 128, Wcn = 128, Cc = 768, WM = 65, NB = 8, BS = 96;
constexpr int NROWS = Bc * WM * Hc;              // 33280 spectral rows (b, wm, h)
constexpr size_t NSPEC = (size_t)NROWS * Cc;     // 25,559,040 elems per r/i plane

typedef __attribute__((ext_vector_type(8))) _Float16 f16x8;
typedef __attribute__((ext_vector_type(4))) float f32x4;
typedef __attribute__((ext_vector_type(4))) unsigned int u32x4;

__device__ __forceinline__ unsigned short f2h(float f) {
    return __builtin_bit_cast(unsigned short, (_Float16)f);
}
__device__ __forceinline__ float h2f(unsigned short s) {
    return (float)__builtin_bit_cast(_Float16, s);
}
// vmcnt-preserving barrier, FENCED both sides (R9 lesson: raw s_barrier is
// not a compiler fence; LDS ops must not be scheduled across it).
__device__ __forceinline__ void barx() {
    __builtin_amdgcn_sched_barrier(0);
    asm volatile("s_waitcnt lgkmcnt(0)" ::: "memory");
    __builtin_amdgcn_s_barrier();
    __builtin_amdgcn_sched_barrier(0);
    asm volatile("" ::: "memory");
}

// ---------------- Kprep: transpose MLP weights to f16 [mat][blk][n][k] ------
__global__ __launch_bounds__(BDIM) void kprep(const float* __restrict__ w1,
                                              const float* __restrict__ w2,
                                              unsigned short* __restrict__ WTg) {
    int idx = blockIdx.x * BDIM + threadIdx.x;   // 4*8*96*96 = 294,912
    if (idx >= 294912) return;
    int k = idx % 96, n = (idx / 96) % 96, blk = (idx / 9216) % 8, mat = idx / 73728;
    const float* src = (mat < 2) ? w1 : w2;
    int q = mat & 1;
    WTg[idx] = f2h(src[(((size_t)q * 8 + blk) * 96 + k) * 96 + n]);
}

// ---------------- K1m: rfft over W via f16 MFMA (scale 1/128) ---------------
// Row-folded square GEMM: M=128 rows = {Yr[0..64], Yi[1..63]}, K=128, N=768.
constexpr int K1PAD = 136;
__global__ __launch_bounds__(BDIM, 1) void k1m(const float* __restrict__ x,
                                               unsigned short* __restrict__ Rr,
                                               unsigned short* __restrict__ Ri) {
    __shared__ unsigned short Xt[64][K1PAD];
    const int tid = threadIdx.x;
    const int lane = tid & 63;
    const int wv = tid >> 6;
    const int b = blockIdx.x >> 7, h = blockIdx.x & 127;
    const float* xp = x + ((size_t)(b * 16384 + h * 128)) * 768;
    const size_t sbase = ((size_t)(b * WM) * 128 + h) * 768;

    f16x8 Af[2][4];
    {
        const int rlo = wv * 32 + (lane & 15);
        #pragma unroll
        for (int rf = 0; rf < 2; ++rf) {
            const int r = rlo + rf * 16;
            const int m = (r < 65) ? r : (r - 64);
            #pragma unroll
            for (int ks = 0; ks < 4; ++ks) {
                f16x8 v;
                #pragma unroll
                for (int j = 0; j < 8; ++j) {
                    int k = ks * 32 + ((lane >> 4) << 3) + j;
                    float th = (float)((m * k) & 127) * 0.04908738521234052f;
                    float s, c; __sincosf(th, &s, &c);
                    v[j] = (_Float16)(((r < 65) ? c : -s) * 0.0078125f);
                }
                Af[rf][ks] = v;
            }
        }
    }

    const int w = tid & 127, cg = tid >> 7;
    float4 pfv[8];
    #pragma unroll
    for (int q = 0; q < 8; ++q)
        pfv[q] = *(const float4*)(xp + (size_t)w * 768 + cg * 32 + q * 4);

    const int koff = (lane >> 4) << 3;

    for (int t = 0; t < 12; ++t) {
        #pragma unroll
        for (int q = 0; q < 8; ++q) {
            float4 v = pfv[q];
            int cb = cg * 32 + q * 4;
            Xt[cb + 0][w] = f2h(v.x);
            Xt[cb + 1][w] = f2h(v.y);
            Xt[cb + 2][w] = f2h(v.z);
            Xt[cb + 3][w] = f2h(v.w);
        }
        if (t < 11) {
            #pragma unroll
            for (int q = 0; q < 8; ++q)
                pfv[q] = *(const float4*)(xp + (size_t)w * 768 + (t + 1) * 64 + cg * 32 + q * 4);
        }
        barx();

        f32x4 acc[2][4];
        #pragma unroll
        for (int rf = 0; rf < 2; ++rf)
            #pragma unroll
            for (int cf = 0; cf < 4; ++cf)
                acc[rf][cf] = (f32x4){0, 0, 0, 0};
        #pragma unroll
        for (int ks = 0; ks < 4; ++ks) {
            #pragma unroll
            for (int cf = 0; cf < 4; ++cf) {
                const int cl = cf * 16 + (lane & 15);
                f16x8 Bf = *(const f16x8*)(&Xt[cl][ks * 32 + koff]);
                #pragma unroll
                for (int rf = 0; rf < 2; ++rf)
                    acc[rf][cf] = __builtin_amdgcn_mfma_f32_16x16x32_f16(Af[rf][ks], Bf, acc[rf][cf], 0, 0, 0);
            }
        }
        #pragma unroll
        for (int rf = 0; rf < 2; ++rf)
            #pragma unroll
            for (int cf = 0; cf < 4; ++cf) {
                int col = t * 64 + cf * 16 + (lane & 15);
                int r0 = wv * 32 + rf * 16 + ((lane >> 4) << 2);
                #pragma unroll
                for (int reg = 0; reg < 4; ++reg) {
                    int r = r0 + reg;
                    if (r < 65) {
                        Rr[sbase + (size_t)r * 98304 + col] = f2h(acc[rf][cf][reg]);
                        if (r == 0)  Ri[sbase + col] = 0;
                        if (r == 64) Ri[sbase + (size_t)64 * 98304 + col] = 0;
                    } else {
                        Ri[sbase + (size_t)(r - 64) * 98304 + col] = f2h(acc[rf][cf][reg]);
                    }
                }
            }
        barx();
    }
}

// ---------------- Kmid: fused fwd H-DFT -> MLP -> inv H-DFT (R10 form) ------
// grid (260 slabs, 8 blocks). 256 threads / 4 waves. In-place on Rr/Ri.
// LDS (121,856 B dyn): Ct[128][136] | St[128][136] | Xt{r,i}[96][136]
//                       (Xt region reused as Y[128][200] for the MLP phases).
constexpr int KMT = 136;
__global__ __launch_bounds__(BDIM, 1) void kmid(unsigned short* __restrict__ Rr,
                                                unsigned short* __restrict__ Ri,
                                                const unsigned short* __restrict__ WTg,
                                                const float* __restrict__ b1,
                                                const float* __restrict__ b2) {
    extern __shared__ unsigned short lds[];
    unsigned short* Ct = lds;                    // [128][136]
    unsigned short* St = Ct + 128 * KMT;         // [128][136]
    unsigned short* Xtr = St + 128 * KMT;        // [96][136]
    unsigned short* Xti = Xtr + 96 * KMT;        // [96][136]
    unsigned short* Y   = Xtr;                   // [128][200] (union)

    const int tid = threadIdx.x;
    const int lane = tid & 63;
    const int wv = tid >> 6;
    const int blk = blockIdx.y;
    const size_t sbase = (size_t)blockIdx.x * 98304;

    // ---- issue X-tile loads (12 x 16B per thread; in flight under sincos)
    const int hme = tid & 127, cgme = tid >> 7;
    u32x4 pfs[12];
    #pragma unroll
    for (int p = 0; p < 12; ++p) {
        const unsigned short* src = (p >= 6) ? Ri : Rr;
        int cg = (p % 6) * 2 + cgme;
        pfs[p] = *(const u32x4*)(src + sbase + (size_t)hme * 768 + blk * 96 + cg * 8);
    }

    // ---- build twiddle tables (p = h2*h mod 128) — overlaps the loads
    for (int idx = tid; idx < 16384; idx += BDIM) {
        int h2 = idx >> 7, h = idx & 127;
        float th = (float)((h2 * h) & 127) * 0.04908738521234052f;
        float sv, cv; __sincosf(th, &sv, &cv);
        Ct[h2 * KMT + h] = f2h(cv);
        St[h2 * KMT + h] = f2h(sv);
    }

    // ---- biases
    const int n0 = wv * 48;
    float bias1[3], bias2[3];
    #pragma unroll
    for (int c = 0; c < 3; ++c) {
        int n = n0 + c * 16 + (lane & 15);
        bias1[c] = (n < 96) ? b1[blk * 96 + n] : b1[768 + blk * 96 + (n - 96)];
        bias2[c] = (n < 96) ? b2[blk * 96 + n] : b2[768 + blk * 96 + (n - 96)];
    }

    // ---- scatter X tile into Xt[c][h] (h lane-major: conflict-free)
    #pragma unroll
    for (int p = 0; p < 12; ++p) {
        unsigned short* dst = (p >= 6) ? Xti : Xtr;
        int cl = ((p % 6) * 2 + cgme) * 8;
        unsigned short tmp[8];
        *(u32x4*)&tmp[0] = pfs[p];
        #pragma unroll
        for (int j = 0; j < 8; ++j)
            dst[(cl + j) * KMT + hme] = tmp[j];
    }
    __syncthreads();   // #1: tables + X staged (nothing usefully in flight)

    const int arow0 = wv * 32 + (lane & 15);
    const int koff = (lane >> 4) << 3;
    const int rowoff = (lane >> 4) << 2;

    // ---- phase A: fwd H-DFT (Yr = C.Xr + S.Xi ; Yi = C.Xi - S.Xr)
    f32x4 accr[2][6], acci[2][6];
    #pragma unroll
    for (int rf = 0; rf < 2; ++rf)
        #pragma unroll
        for (int cf = 0; cf < 6; ++cf) {
            accr[rf][cf] = (f32x4){0, 0, 0, 0};
            acci[rf][cf] = (f32x4){0, 0, 0, 0};
        }
    #pragma unroll
    for (int ks = 0; ks < 4; ++ks) {
        f16x8 Cf[2], Sp[2], Sn[2];
        #pragma unroll
        for (int rf = 0; rf < 2; ++rf) {
            int off = (arow0 + rf * 16) * KMT + ks * 32 + koff;
            Cf[rf] = *(const f16x8*)(Ct + off);
            f16x8 sv = *(const f16x8*)(St + off);
            u32x4 u = __builtin_bit_cast(u32x4, sv);
            u ^= 0x80008000u;
            Sp[rf] = sv;
            Sn[rf] = __builtin_bit_cast(f16x8, u);
        }
        #pragma unroll
        for (int cf = 0; cf < 6; ++cf) {
            int boff = (cf * 16 + (lane & 15)) * KMT + ks * 32 + koff;
            f16x8 Br = *(const f16x8*)(Xtr + boff);
            f16x8 Bi = *(const f16x8*)(Xti + boff);
            #pragma unroll
            for (int rf = 0; rf < 2; ++rf) {
                accr[rf][cf] = __builtin_amdgcn_mfma_f32_16x16x32_f16(Cf[rf], Br, accr[rf][cf], 0, 0, 0);
                accr[rf][cf] = __builtin_amdgcn_mfma_f32_16x16x32_f16(Sp[rf], Bi, accr[rf][cf], 0, 0, 0);
                acci[rf][cf] = __builtin_amdgcn_mfma_f32_16x16x32_f16(Cf[rf], Bi, acci[rf][cf], 0, 0, 0);
                acci[rf][cf] = __builtin_amdgcn_mfma_f32_16x16x32_f16(Sn[rf], Br, acci[rf][cf], 0, 0, 0);
            }
        }
    }

    // ---- issue weight-fragment loads (used in phase B; overlap Y writes)
    f16x8 Bf1[3][6], Bf2[3][6];
    #pragma unroll
    for (int c = 0; c < 3; ++c) {
        const int nq = (n0 + c * 16) < 96;
        const int nl = n0 + c * 16 + (lane & 15) - (nq ? 0 : 96);
        #pragma unroll
        for (int kit = 0; kit < 6; ++kit) {
            const int kq = kit < 3;
            const int kl = kit * 32 + koff - (kq ? 0 : 96);
            const int quad = kq ? (nq ? 0 : 1) : (nq ? 1 : 0);
            const bool flip = (!kq) && nq;
            {
                f16x8 v = *(const f16x8*)(WTg + ((size_t)(quad * 8 + blk) * 96 + nl) * 96 + kl);
                if (flip) { u32x4 u = __builtin_bit_cast(u32x4, v); u ^= 0x80008000u; v = __builtin_bit_cast(f16x8, u); }
                Bf1[c][kit] = v;
            }
            {
                f16x8 v = *(const f16x8*)(WTg + ((size_t)((2 + quad) * 8 + blk) * 96 + nl) * 96 + kl);
                if (flip) { u32x4 u = __builtin_bit_cast(u32x4, v); u ^= 0x80008000u; v = __builtin_bit_cast(f16x8, u); }
                Bf2[c][kit] = v;
            }
        }
    }

    barx();   // #2: all Xt reads done; region becomes Y (weight loads in flight)
    // ---- write Y [pos][k] augmented (k<96 = real, k>=96 = imag)
    #pragma unroll
    for (int rf = 0; rf < 2; ++rf)
        #pragma unroll
        for (int cf = 0; cf < 6; ++cf) {
            int c = cf * 16 + (lane & 15);
            #pragma unroll
            for (int reg = 0; reg < 4; ++reg) {
                int row = wv * 32 + rf * 16 + rowoff + reg;
                Y[row * 200 + c]      = f2h(accr[rf][cf][reg]);
                Y[row * 200 + 96 + c] = f2h(acci[rf][cf][reg]);
            }
        }
    barx();   // #3: Y visible (weight loads still in flight)

    // ---- phase B: MLP layer 1
    const unsigned short* Xl = Y + (lane & 15) * 200 + ((lane >> 4) << 3);
    f32x4 acc[8][3];
    #pragma unroll
    for (int r = 0; r < 8; ++r)
        #pragma unroll
        for (int c = 0; c < 3; ++c)
            acc[r][c] = (f32x4){bias1[c], bias1[c], bias1[c], bias1[c]};
    #pragma unroll
    for (int kit = 0; kit < 6; ++kit) {
        f16x8 A[8];
        #pragma unroll
        for (int r = 0; r < 8; ++r)
            A[r] = *(const f16x8*)(Xl + r * 3200 + kit * 32);
        #pragma unroll
        for (int r = 0; r < 8; ++r)
            #pragma unroll
            for (int c = 0; c < 3; ++c)
                acc[r][c] = __builtin_amdgcn_mfma_f32_16x16x32_f16(A[r], Bf1[c][kit], acc[r][c], 0, 0, 0);
    }
    __syncthreads();   // #4: layer-1 A-reads done (vmem queue empty by now)
    #pragma unroll
    for (int r = 0; r < 8; ++r)
        #pragma unroll
        for (int c = 0; c < 3; ++c) {
            int ncol = n0 + c * 16 + (lane & 15);
            #pragma unroll
            for (int reg = 0; reg < 4; ++reg) {
                int row = r * 16 + rowoff + reg;
                Y[row * 200 + ncol] = f2h(fmaxf(acc[r][c][reg], 0.f));
            }
        }
    __syncthreads();   // #5: O1 visible

    // ---- layer 2 + softshrink
    #pragma unroll
    for (int r = 0; r < 8; ++r)
        #pragma unroll
        for (int c = 0; c < 3; ++c)
            acc[r][c] = (f32x4){bias2[c], bias2[c], bias2[c], bias2[c]};
    #pragma unroll
    for (int kit = 0; kit < 6; ++kit) {
        f16x8 A[8];
        #pragma unroll
        for (int r = 0; r < 8; ++r)
            A[r] = *(const f16x8*)(Xl + r * 3200 + kit * 32);
        #pragma unroll
        for (int r = 0; r < 8; ++r)
            #pragma unroll
            for (int c = 0; c < 3; ++c)
                acc[r][c] = __builtin_amdgcn_mfma_f32_16x16x32_f16(A[r], Bf2[c][kit], acc[r][c], 0, 0, 0);
    }
    __syncthreads();   // #6: layer-2 A-reads done; region becomes Xt again
    // ---- write O2 transposed into Xt[c][h2] with softshrink
    #pragma unroll
    for (int r = 0; r < 8; ++r)
        #pragma unroll
        for (int c = 0; c < 3; ++c) {
            int ncol = n0 + c * 16 + (lane & 15);
            unsigned short* dst = (ncol < 96) ? Xtr : Xti;
            int cc = (ncol < 96) ? ncol : ncol - 96;
            #pragma unroll
            for (int reg = 0; reg < 4; ++reg) {
                int row = r * 16 + rowoff + reg;
                float v = acc[r][c][reg];
                v = (v > 0.01f) ? v - 0.01f : ((v < -0.01f) ? v + 0.01f : 0.f);
                dst[cc * KMT + row] = f2h(v);
            }
        }
    __syncthreads();   // #7: O2t visible

    // ---- phase C: inverse H-DFT (Zr = C.Or - S.Oi ; Zi = C.Oi + S.Or)
    #pragma unroll
    for (int rf = 0; rf < 2; ++rf)
        #pragma unroll
        for (int cf = 0; cf < 6; ++cf) {
            accr[rf][cf] = (f32x4){0, 0, 0, 0};
            acci[rf][cf] = (f32x4){0, 0, 0, 0};
        }
    #pragma unroll
    for (int ks = 0; ks < 4; ++ks) {
        f16x8 Cf[2], Sp[2], Sn[2];
        #pragma unroll
        for (int rf = 0; rf < 2; ++rf) {
            int off = (arow0 + rf * 16) * KMT + ks * 32 + koff;
            Cf[rf] = *(const f16x8*)(Ct + off);
            f16x8 sv = *(const f16x8*)(St + off);
            u32x4 u = __builtin_bit_cast(u32x4, sv);
            u ^= 0x80008000u;
            Sp[rf] = sv;
            Sn[rf] = __builtin_bit_cast(f16x8, u);
        }
        #pragma unroll
        for (int cf = 0; cf < 6; ++cf) {
            int boff = (cf * 16 + (lane & 15)) * KMT + ks * 32 + koff;
            f16x8 Br = *(const f16x8*)(Xtr + boff);
            f16x8 Bi = *(const f16x8*)(Xti + boff);
            #pragma unroll
            for (int rf = 0; rf < 2; ++rf) {
                accr[rf][cf] = __builtin_amdgcn_mfma_f32_16x16x32_f16(Cf[rf], Br, accr[rf][cf], 0, 0, 0);
                accr[rf][cf] = __builtin_amdgcn_mfma_f32_16x16x32_f16(Sn[rf], Bi, accr[rf][cf], 0, 0, 0);
                acci[rf][cf] = __builtin_amdgcn_mfma_f32_16x16x32_f16(Cf[rf], Bi, acci[rf][cf], 0, 0, 0);
                acci[rf][cf] = __builtin_amdgcn_mfma_f32_16x16x32_f16(Sp[rf], Br, acci[rf][cf], 0, 0, 0);
            }
        }
    }
    // ---- store to global spectral planes (in place)
    #pragma unroll
    for (int rf = 0; rf < 2; ++rf)
        #pragma unroll
        for (int cf = 0; cf < 6; ++cf) {
            int c = blk * 96 + cf * 16 + (lane & 15);
            int h0 = wv * 32 + rf * 16 + rowoff;
            #pragma unroll
            for (int reg = 0; reg < 4; ++reg) {
                size_t a = sbase + (size_t)(h0 + reg) * 768 + c;
                Rr[a] = f2h(accr[rf][cf][reg]);
                Ri[a] = f2h(acci[rf][cf][reg]);
            }
        }
}

// ---------------- K5m: c2r inverse over W via f16 MFMA + residual -----------
constexpr int K5PAD = 104;
__global__ __launch_bounds__(BDIM, 1) void k5m(const unsigned short* __restrict__ Rr,
                                               const unsigned short* __restrict__ Ri,
                                               const float* __restrict__ x,
                                               float* __restrict__ out) {
    __shared__ unsigned short Xt[2][64][K5PAD];
    const int tid = threadIdx.x;
    const int lane = tid & 63;
    const int wv = tid >> 6;
    const int b = blockIdx.x >> 7, h = blockIdx.x & 127;
    const size_t rowbase = ((size_t)(b * WM) * 128 + h) * 768;
    const size_t obase = ((size_t)(b * 16384 + h * 128)) * 768;

    f16x8 Ca[2][3], Sa[2][3];
    {
        const int wrow_lo = wv * 32 + (lane & 15);
        #pragma unroll
        for (int rf = 0; rf < 2; ++rf) {
            const int wrow = wrow_lo + rf * 16;
            #pragma unroll
            for (int ks = 0; ks < 3; ++ks) {
                f16x8 cv, sv;
                #pragma unroll
                for (int j = 0; j < 8; ++j) {
                    int wm = ks * 32 + ((lane >> 4) << 3) + j;
                    float alpha = (wm > 64) ? 0.f : ((wm == 0 || wm == 64) ? 1.f : 2.f);
                    float th = (float)((wrow * wm) & 127) * 0.04908738521234052f;
                    float s, c; __sincosf(th, &s, &c);
                    cv[j] = (_Float16)(alpha * 0.0078125f * c);
                    sv[j] = (_Float16)(-alpha * 0.0078125f * s);
                }
                Ca[rf][ks] = cv;
                Sa[rf][ks] = sv;
            }
        }
    }

    for (int idx = tid; idx < 2 * 64 * 31; idx += BDIM) {
        int plane = idx / (64 * 31), rem = idx % (64 * 31);
        int cl = rem / 31, wm = 65 + rem % 31;
        Xt[plane][cl][wm] = 0;
    }

    unsigned short pfs[4][8], pfn[8];
    #pragma unroll
    for (int i = 0; i < 4; ++i) {
        const unsigned short* src = (i >> 1) ? Ri : Rr;
        int grp = (i & 1) * 4 + wv;
        *(u32x4*)&pfs[i][0] = *(const u32x4*)(src + rowbase + (size_t)lane * 98304 + grp * 8);
    }
    if (tid < 16) {
        const unsigned short* src = (tid >> 3) ? Ri : Rr;
        *(u32x4*)&pfn[0] = *(const u32x4*)(src + rowbase + (size_t)64 * 98304 + (tid & 7) * 8);
    }

    for (int t = 0; t < 12; ++t) {
        #pragma unroll
        for (int i = 0; i < 4; ++i) {
            int plane = i >> 1, grp = (i & 1) * 4 + wv;
            #pragma unroll
            for (int j = 0; j < 8; ++j)
                Xt[plane][grp * 8 + j][lane] = pfs[i][j];
        }
        if (tid < 16) {
            int plane = tid >> 3, grp = tid & 7;
            #pragma unroll
            for (int j = 0; j < 8; ++j)
                Xt[plane][grp * 8 + j][64] = pfn[j];
        }
        if (t < 11) {
            #pragma unroll
            for (int i = 0; i < 4; ++i) {
                const unsigned short* src = (i >> 1) ? Ri : Rr;
                int grp = (i & 1) * 4 + wv;
                *(u32x4*)&pfs[i][0] = *(const u32x4*)(src + rowbase + (size_t)lane * 98304 + (t + 1) * 64 + grp * 8);
            }
            if (tid < 16) {
                const unsigned short* src = (tid >> 3) ? Ri : Rr;
                *(u32x4*)&pfn[0] = *(const u32x4*)(src + rowbase + (size_t)64 * 98304 + (t + 1) * 64 + (tid & 7) * 8);
            }
        }
        barx();

        f32x4 acc[2][4];
        #pragma unroll
        for (int rf = 0; rf < 2; ++rf)
            #pragma unroll
            for (int cf = 0; cf < 4; ++cf)
                acc[rf][cf] = (f32x4){0, 0, 0, 0};
        const int koff = (lane >> 4) << 3;
        #pragma unroll
        for (int ks = 0; ks < 3; ++ks) {
            #pragma unroll
            for (int cf = 0; cf < 4; ++cf) {
                const int cl = cf * 16 + (lane & 15);
                f16x8 Br = *(const f16x8*)(&Xt[0][cl][ks * 32 + koff]);
                f16x8 Bi = *(const f16x8*)(&Xt[1][cl][ks * 32 + koff]);
                #pragma unroll
                for (int rf = 0; rf < 2; ++rf) {
                    acc[rf][cf] = __builtin_amdgcn_mfma_f32_16x16x32_f16(Ca[rf][ks], Br, acc[rf][cf], 0, 0, 0);
                    acc[rf][cf] = __builtin_amdgcn_mfma_f32_16x16x32_f16(Sa[rf][ks], Bi, acc[rf][cf], 0, 0, 0);
                }
            }
        }
        #pragma unroll
        for (int rf = 0; rf < 2; ++rf)
            #pragma unroll
            for (int cf = 0; cf < 4; ++cf) {
                int col = t * 64 + cf * 16 + (lane & 15);
                int row0 = wv * 32 + rf * 16 + ((lane >> 4) << 2);
                #pragma unroll
                for (int reg = 0; reg < 4; ++reg) {
                    size_t a = obase + (size_t)(row0 + reg) * 768 + col;
                    out[a] = acc[rf][cf][reg] + x[a];
                }
            }
        barx();
    }
}

extern "C" void kernel_launch(void* const* d_in, const int* in_sizes, int n_in,
                              void* d_out, int out_size, void* d_ws, size_t ws_size,
                              hipStream_t stream) {
    const float* x  = (const float*)d_in[0];
    const float* w1 = (const float*)d_in[1];
    const float* b1 = (const float*)d_in[2];
    const float* w2 = (const float*)d_in[3];
    const float* b2 = (const float*)d_in[4];
    float* out = (float*)d_out;

    unsigned short* Rr = (unsigned short*)d_ws;
    unsigned short* Ri = Rr + NSPEC;
    unsigned short* WTg = Ri + NSPEC;            // 294,912 f16 = 0.6 MB

    const size_t kmlds = (size_t)(2 * 128 * KMT + 2 * 96 * KMT) * 2;  // 121,856 B

    kprep<<<dim3(1152), BDIM, 0, stream>>>(w1, w2, WTg);
    k1m<<<dim3(512), BDIM, 0, stream>>>(x, Rr, Ri);
    kmid<<<dim3(260, 8), BDIM, kmlds, stream>>>(Rr, Ri, WTg, b1, b2);
    k5m<<<dim3(512), BDIM, 0, stream>>>(Rr, Ri, x, out);
}